// Round 7
// baseline (254.062 us; speedup 1.0000x reference)
//
#include <hip/hip_runtime.h>

typedef __attribute__((ext_vector_type(8))) short short8_t;  // 8 bf16 (4 VGPRs)
typedef __attribute__((ext_vector_type(4))) float float4_t;  // MFMA C/D
typedef unsigned short u16;
typedef unsigned int u32;
typedef unsigned long long u64;

// ---------- helpers ----------
__device__ inline u16 f2bf(float x) {
  union { float f; u32 u; } v; v.f = x;
  u32 r = v.u + 0x7FFFu + ((v.u >> 16) & 1u);  // round-to-nearest-even
  return (u16)(r >> 16);
}
#if __has_builtin(__builtin_amdgcn_cvt_pk_bf16_f32)
typedef __attribute__((ext_vector_type(2))) __bf16 bf162_t;
__device__ inline u32 pk2(float a, float b) {   // v_cvt_pk_bf16_f32: low=a, high=b, RNE
  union { bf162_t v; u32 u; } cv;
  cv.v = __builtin_amdgcn_cvt_pk_bf16_f32(a, b);
  return cv.u;
}
#else
__device__ inline u32 pk2(float a, float b) {
  return (u32)f2bf(a) | ((u32)f2bf(b) << 16);
}
#endif
// async global->LDS DMA, 16B per lane; lds dest = wave-uniform base + lane*16
__device__ inline void async16(const u16* g, u16* l) {
  __builtin_amdgcn_global_load_lds(
      (const __attribute__((address_space(1))) unsigned int*)g,
      (__attribute__((address_space(3))) unsigned int*)l, 16, 0, 0);
}

// ---------- fused prologue: X fp32->bf16 (blocks 0..4095), W transposes (4096..8191) ----------
__global__ __launch_bounds__(256) void prologue(const float* __restrict__ X,
                                                const float* __restrict__ Wq, const float* __restrict__ Wk,
                                                const float* __restrict__ Wv, const float* __restrict__ Wo,
                                                u16* __restrict__ Xb, u16* __restrict__ WqkvT,
                                                u16* __restrict__ WoT) {
  __shared__ float tls[32][33];
  int bid = blockIdx.x;
  if (bid < 4096) {
    int i = bid * 256 + threadIdx.x;  // one float4 per thread
    float4_t x = ((const float4_t*)X)[i];
    union { u32 u[2]; u64 ll; } o;
    o.u[0] = pk2(x[0], x[1]);
    o.u[1] = pk2(x[2], x[3]);
    ((u64*)Xb)[i] = o.ll;
  } else {
    int t = bid - 4096;
    int mat = t >> 10, tile = t & 1023;
    const float* W = (mat == 0) ? Wq : (mat == 1) ? Wk : (mat == 2) ? Wv : Wo;
    u16* WT = (mat < 3) ? WqkvT + ((size_t)mat << 20) : WoT;
    int tx = threadIdx.x & 31, ty = threadIdx.x >> 5;  // 32 x 8
    int c0 = (tile & 31) * 32, r0 = (tile >> 5) * 32;  // r0: k, c0: n
    #pragma unroll
    for (int i = 0; i < 4; ++i)
      tls[ty + i * 8][tx] = W[(r0 + ty + i * 8) * 1024 + c0 + tx];
    __syncthreads();
    #pragma unroll
    for (int i = 0; i < 4; ++i)
      WT[(size_t)(c0 + ty + i * 8) * 1024 + r0 + tx] = f2bf(tls[tx][ty + i * 8]);
  }
}

// ---------- GEMM: 128x128 C-tile, 4 waves each 64x64, BK=64 ----------
// 1D grid with L2-locality swizzle (mode 4: 16-m x n panels). LDS staged via
// global_load_lds; XOR chunk swizzle applied at global SOURCE address.
// mode 4 (fused QKV, 768 blocks): col block 0->Q(x0.125) o0 [B,H,S,64], 1->K o1,
//   2->V o2 [B,H,64,S] (transposed). mode 3 (O-proj, 256 blocks): fp32 out o0.
__global__ __launch_bounds__(256) void gemm128(const u16* __restrict__ A, const u16* __restrict__ BT,
                                               const float* __restrict__ bias0, const float* __restrict__ bias1,
                                               const float* __restrict__ bias2,
                                               void* __restrict__ o0, void* __restrict__ o1, void* __restrict__ o2,
                                               int mode) {
  __shared__ __align__(16) u16 Als[128 * 64];  // 16 KB
  __shared__ __align__(16) u16 Bls[128 * 64];  // 16 KB
  int g = blockIdx.x, m0t, n0t;
  if (mode == 4) {  // 768 blocks: panels of 16 m-tiles x 24 n-tiles
    int mh = g / 384, r = g - mh * 384;
    n0t = r >> 4;
    m0t = mh * 16 + (r & 15);
  } else {          // 256 blocks
    m0t = g & 31;
    n0t = g >> 5;
  }
  const int m0 = m0t * 128, n0 = n0t * 128;
  const int lane = threadIdx.x & 63, wave = threadIdx.x >> 6;
  const int quad = lane >> 4, c = lane & 15;
  const int wm = wave >> 1, wn = wave & 1;

  // staging: call q stages rows wave*32+q*8 .. +7 (8 rows x 8 chunks = 64 lanes)
  const int srow = lane >> 3, schunk = lane & 7;
  int soff[4];  u16 *lA[4], *lB[4];
  #pragma unroll
  for (int q = 0; q < 4; ++q) {
    int r = wave * 32 + q * 8 + srow;
    soff[q] = r * 1024 + ((schunk ^ (r & 7)) << 3);
    lA[q] = &Als[(wave * 32 + q * 8) * 64 + lane * 8];
    lB[q] = &Bls[(wave * 32 + q * 8) * 64 + lane * 8];
  }
  const u16* gA = A + (size_t)m0 * 1024;
  const u16* gB = BT + (size_t)n0 * 1024;

  int ar[2][4], br[2][4];
  #pragma unroll
  for (int ko = 0; ko < 2; ++ko) {
    #pragma unroll
    for (int i = 0; i < 4; ++i) {
      int rowa = wm * 64 + i * 16 + c;
      ar[ko][i] = rowa * 64 + (((ko * 4 + quad) ^ (rowa & 7)) << 3);
      int rowb = wn * 64 + i * 16 + c;
      br[ko][i] = rowb * 64 + (((ko * 4 + quad) ^ (rowb & 7)) << 3);
    }
  }

  float4_t acc[4][4] = {};
  for (int k0 = 0; k0 < 1024; k0 += 64) {
    #pragma unroll
    for (int q = 0; q < 4; ++q) async16(gA + soff[q] + k0, lA[q]);
    #pragma unroll
    for (int q = 0; q < 4; ++q) async16(gB + soff[q] + k0, lB[q]);
    __syncthreads();
    #pragma unroll
    for (int ko = 0; ko < 2; ++ko) {
      short8_t af[4], bfr[4];
      #pragma unroll
      for (int i = 0; i < 4; ++i) af[i] = *(const short8_t*)&Als[ar[ko][i]];
      #pragma unroll
      for (int j = 0; j < 4; ++j) bfr[j] = *(const short8_t*)&Bls[br[ko][j]];
      #pragma unroll
      for (int i = 0; i < 4; ++i)
        #pragma unroll
        for (int j = 0; j < 4; ++j)
          acc[i][j] = __builtin_amdgcn_mfma_f32_16x16x32_bf16(af[i], bfr[j], acc[i][j], 0, 0, 0);
    }
    __syncthreads();
  }

  const int mrow = m0 + wm * 64, ncol = n0 + wn * 64;
  if (mode == 3) {
    float* o = (float*)o0;
    #pragma unroll
    for (int i = 0; i < 4; ++i) {
      #pragma unroll
      for (int j = 0; j < 4; ++j) {
        int colb = ncol + j * 16 + c;
        float bv = bias0[colb];
        int rowb = mrow + i * 16 + quad * 4;
        #pragma unroll
        for (int r = 0; r < 4; ++r)
          o[(size_t)(rowb + r) * 1024 + colb] = acc[i][j][r] + bv;
      }
    }
  } else {
    #pragma unroll
    for (int j = 0; j < 4; ++j) {
      int colb = ncol + j * 16 + c;     // 0..3071
      int which = colb >> 10;           // 0:Q 1:K 2:V (uniform per j)
      int n1 = colb & 1023, h = n1 >> 6, d = n1 & 63;
      const float* bp = (which == 0) ? bias0 : (which == 1 ? bias1 : bias2);
      float bv = bp[n1];
      #pragma unroll
      for (int i = 0; i < 4; ++i) {
        int rowb = mrow + i * 16 + quad * 4;
        int b = rowb >> 11, s = rowb & 2047;
        if (which == 2) {
          u16* o = (u16*)o2 + (((size_t)(b * 16 + h) * 64 + d) * 2048 + s);
          union { u32 u[2]; u64 ll; } ov;
          ov.u[0] = pk2(acc[i][j][0] + bv, acc[i][j][1] + bv);
          ov.u[1] = pk2(acc[i][j][2] + bv, acc[i][j][3] + bv);
          *(u64*)o = ov.ll;
        } else {
          float sc = (which == 0) ? 0.125f : 1.0f;
          u16* o = (u16*)((which == 0) ? o0 : o1);
          #pragma unroll
          for (int r = 0; r < 4; ++r)
            o[(((size_t)(b * 16 + h) * 2048 + (s + r)) << 6) + d] = f2bf((acc[i][j][r] + bv) * sc);
        }
      }
    }
  }
}

// P^T C-layout -> 16x16x32 B-operand layout via packed-bf16 shuffles
__device__ inline short8_t p_to_b32(const float* p, int quad, int c) {
  u32 pk0[2] = {pk2(p[0], p[1]), pk2(p[2], p[3])};
  u32 pk1[2] = {pk2(p[4], p[5]), pk2(p[6], p[7])};
  int base = ((quad & 1) * 2) * 16 + c;
  union { u32 u[4]; short8_t v; } pf;
  #pragma unroll
  for (int x = 0; x < 4; ++x) {
    int src = base + ((x >> 1) << 4);
    int v0 = __shfl((int)pk0[x & 1], src);
    int v1 = __shfl((int)pk1[x & 1], src);
    pf.u[x] = (quad < 2) ? (u32)v0 : (u32)v1;
  }
  return pf.v;
}

// K/V register tile for one 32-key step
struct KV {
  short8_t ka0, ka1, kb0, kb1, v0, v1, v2, v3;
};
__device__ inline KV load_kv(const u16* __restrict__ Kp, const u16* __restrict__ Vp,
                             int kbase, int quad, int c) {
  KV r;
  const u16* kp = Kp + (((size_t)kbase + c) << 6) + quad * 8;
  r.ka0 = *(const short8_t*)(kp);
  r.ka1 = *(const short8_t*)(kp + 32);
  r.kb0 = *(const short8_t*)(kp + 1024);
  r.kb1 = *(const short8_t*)(kp + 1024 + 32);
  const u16* vp = Vp + (size_t)c * 2048 + kbase + quad * 8;
  r.v0 = *(const short8_t*)(vp);
  r.v1 = *(const short8_t*)(vp + 16 * 2048);
  r.v2 = *(const short8_t*)(vp + 32 * 2048);
  r.v3 = *(const short8_t*)(vp + 48 * 2048);
  return r;
}

// ---------- flash attention: 8-wave blocks, 8-way K-split, depth-1 prefetch ----------
// Q,K: [B,H,S,64] bf16 (Q pre-scaled 1/8); VT: [B,H,64,S]; ctx: [B,S,1024] bf16.
// Grid 2048 x 512: block = one (bh, 32-query unit); u = 63-(g>>5) -> heavy first;
// g&7 spreads bh across XCDs. 8 waves split K strided-by-8. Fixed-base softmax
// (no running max; masked scores -> exp2(-large)=0) -> partials additively
// combinable; combine via 34.8 KB LDS.
// Software pipeline: next iteration's K/V fragments are loaded before this
// iteration's compute, hiding the L3/L2 load latency behind softmax VALU work.
// Causal cndmask only on the (wave-uniform) diagonal iteration.
__global__ __launch_bounds__(512) void attn_kernel(const u16* __restrict__ Q, const u16* __restrict__ K,
                                                   const u16* __restrict__ VT, const float* __restrict__ mask,
                                                   u16* __restrict__ ctx) {
  __shared__ float cmb[8][64][17];
  const float C1 = 10000.0f * 1.4426950408889634f;
  const float LOG2E = 1.4426950408889634f;
  int w = threadIdx.x >> 6, lane = threadIdx.x & 63;
  int quad = lane >> 4, c = lane & 15;
  int g = blockIdx.x;
  int bh = (g & 7) * 4 + ((g >> 3) & 3);   // XCD-affine
  int u = 63 - (g >> 5);                    // heavy first
  int b = bh >> 4, h = bh & 15;
  const u16* Kp = K + ((size_t)bh << 17);
  const u16* Vp = VT + ((size_t)bh << 17);
  const float* mp = mask + (b << 11);

  int q0 = u << 5;
  const u16* Qp = Q + (((size_t)bh * 2048 + q0 + c) << 6) + quad * 8;
  short8_t qA0 = *(const short8_t*)(Qp);
  short8_t qA1 = *(const short8_t*)(Qp + 32);
  short8_t qB0 = *(const short8_t*)(Qp + 1024);
  short8_t qB1 = *(const short8_t*)(Qp + 1024 + 32);
  float4_t OA[4] = {}, OB[4] = {};
  float lA = 0.0f, lB = 0.0f;
  int qgA = q0 + c, qgB = q0 + 16 + c;
  // per-lane kpos offsets within a 32-key tile (constant across iterations)
  int ke[8];
  #pragma unroll
  for (int e = 0; e < 8; ++e) ke[e] = ((e >> 2) << 4) + quad * 4 + (e & 3);

  KV cur = load_kv(Kp, Vp, w << 5, quad, c);
  for (int t = w; t <= u; t += 8) {
    int tn = (t + 8 <= u) ? (t + 8) : t;   // clamped prefetch (last iter: dummy reload)
    KV nxt = load_kv(Kp, Vp, tn << 5, quad, c);
    int kbase = t << 5;
    float4_t mv0 = *(const float4_t*)(mp + kbase + quad * 4);
    float4_t mv1 = *(const float4_t*)(mp + kbase + 16 + quad * 4);
    float4_t mpl0 = (mv0 - 1.0f) * C1;  // (1-m)*-10000*log2e
    float4_t mpl1 = (mv1 - 1.0f) * C1;
    // S^T = K_tile @ Q^T
    float4_t sA0 = {}, sA1 = {}, sB0 = {}, sB1 = {};
    sA0 = __builtin_amdgcn_mfma_f32_16x16x32_bf16(cur.ka0, qA0, sA0, 0, 0, 0);
    sA0 = __builtin_amdgcn_mfma_f32_16x16x32_bf16(cur.ka1, qA1, sA0, 0, 0, 0);
    sA1 = __builtin_amdgcn_mfma_f32_16x16x32_bf16(cur.kb0, qA0, sA1, 0, 0, 0);
    sA1 = __builtin_amdgcn_mfma_f32_16x16x32_bf16(cur.kb1, qA1, sA1, 0, 0, 0);
    sB0 = __builtin_amdgcn_mfma_f32_16x16x32_bf16(cur.ka0, qB0, sB0, 0, 0, 0);
    sB0 = __builtin_amdgcn_mfma_f32_16x16x32_bf16(cur.ka1, qB1, sB0, 0, 0, 0);
    sB1 = __builtin_amdgcn_mfma_f32_16x16x32_bf16(cur.kb0, qB0, sB1, 0, 0, 0);
    sB1 = __builtin_amdgcn_mfma_f32_16x16x32_bf16(cur.kb1, qB1, sB1, 0, 0, 0);
    float pA[8], pB[8];
    #pragma unroll
    for (int e = 0; e < 8; ++e) {
      float svA = (e < 4) ? sA0[e] : sA1[e - 4];
      float svB = (e < 4) ? sB0[e] : sB1[e - 4];
      float ml = (e < 4) ? mpl0[e] : mpl1[e - 4];
      pA[e] = __builtin_fmaf(svA, LOG2E, ml);
      pB[e] = __builtin_fmaf(svB, LOG2E, ml);
    }
    if (t == u) {  // wave-uniform: only the diagonal-owning iteration pays
      int thrA = qgA - kbase, thrB = qgB - kbase;
      #pragma unroll
      for (int e = 0; e < 8; ++e) {
        pA[e] = (ke[e] > thrA) ? -50.0f : pA[e];
        pB[e] = (ke[e] > thrB) ? -50.0f : pB[e];
      }
    }
    #pragma unroll
    for (int e = 0; e < 8; ++e) {
      float peA = exp2f(pA[e]);
      float peB = exp2f(pB[e]);
      pA[e] = peA; lA += peA;
      pB[e] = peB; lB += peB;
    }
    short8_t pfA = p_to_b32(pA, quad, c);
    short8_t pfB = p_to_b32(pB, quad, c);
    // ctx^T += V^T_tile @ P^T
    OA[0] = __builtin_amdgcn_mfma_f32_16x16x32_bf16(cur.v0, pfA, OA[0], 0, 0, 0);
    OA[1] = __builtin_amdgcn_mfma_f32_16x16x32_bf16(cur.v1, pfA, OA[1], 0, 0, 0);
    OA[2] = __builtin_amdgcn_mfma_f32_16x16x32_bf16(cur.v2, pfA, OA[2], 0, 0, 0);
    OA[3] = __builtin_amdgcn_mfma_f32_16x16x32_bf16(cur.v3, pfA, OA[3], 0, 0, 0);
    OB[0] = __builtin_amdgcn_mfma_f32_16x16x32_bf16(cur.v0, pfB, OB[0], 0, 0, 0);
    OB[1] = __builtin_amdgcn_mfma_f32_16x16x32_bf16(cur.v1, pfB, OB[1], 0, 0, 0);
    OB[2] = __builtin_amdgcn_mfma_f32_16x16x32_bf16(cur.v2, pfB, OB[2], 0, 0, 0);
    OB[3] = __builtin_amdgcn_mfma_f32_16x16x32_bf16(cur.v3, pfB, OB[3], 0, 0, 0);
    cur = nxt;
  }
  // ---- combine half A (waves 0-3 reduce) ----
  float* cw = &cmb[w][lane][0];
  #pragma unroll
  for (int d = 0; d < 4; ++d)
    #pragma unroll
    for (int r = 0; r < 4; ++r) cw[d * 4 + r] = OA[d][r];
  cw[16] = lA;
  __syncthreads();
  if (w < 4) {
    float4_t s = {};
    float la = 0.0f;
    #pragma unroll
    for (int w2 = 0; w2 < 8; ++w2) {
      const float* cr = &cmb[w2][lane][0];
      #pragma unroll
      for (int r = 0; r < 4; ++r) s[r] += cr[w * 4 + r];
      la += cr[16];
    }
    la += __shfl_xor(la, 16); la += __shfl_xor(la, 32);
    float rA = 1.0f / la;
    u16* op = ctx + ((size_t)(b * 2048 + q0 + c) * 1024 + h * 64 + w * 16 + quad * 4);
    union { u32 uu[2]; u64 ll; } ov;
    ov.uu[0] = pk2(s[0] * rA, s[1] * rA);
    ov.uu[1] = pk2(s[2] * rA, s[3] * rA);
    *(u64*)op = ov.ll;
  }
  __syncthreads();
  // ---- combine half B (waves 4-7 reduce) ----
  #pragma unroll
  for (int d = 0; d < 4; ++d)
    #pragma unroll
    for (int r = 0; r < 4; ++r) cw[d * 4 + r] = OB[d][r];
  cw[16] = lB;
  __syncthreads();
  if (w >= 4) {
    int dblk = w - 4;
    float4_t s = {};
    float lb = 0.0f;
    #pragma unroll
    for (int w2 = 0; w2 < 8; ++w2) {
      const float* cr = &cmb[w2][lane][0];
      #pragma unroll
      for (int r = 0; r < 4; ++r) s[r] += cr[dblk * 4 + r];
      lb += cr[16];
    }
    lb += __shfl_xor(lb, 16); lb += __shfl_xor(lb, 32);
    float rB = 1.0f / lb;
    u16* op = ctx + ((size_t)(b * 2048 + q0 + 16 + c) * 1024 + h * 64 + dblk * 16 + quad * 4);
    union { u32 uu[2]; u64 ll; } ov;
    ov.uu[0] = pk2(s[0] * rB, s[1] * rB);
    ov.uu[1] = pk2(s[2] * rB, s[3] * rB);
    *(u64*)op = ov.ll;
  }
}

// ---------- launch ----------
extern "C" void kernel_launch(void* const* d_in, const int* in_sizes, int n_in,
                              void* d_out, int out_size, void* d_ws, size_t ws_size,
                              hipStream_t stream) {
  const float* X    = (const float*)d_in[0];
  const float* mask = (const float*)d_in[1];
  const float* Wq   = (const float*)d_in[2];
  const float* bq   = (const float*)d_in[3];
  const float* Wk   = (const float*)d_in[4];
  const float* bk   = (const float*)d_in[5];
  const float* Wv   = (const float*)d_in[6];
  const float* bv   = (const float*)d_in[7];
  const float* Wo   = (const float*)d_in[8];
  const float* bo   = (const float*)d_in[9];

  char* w = (char*)d_ws;
  u16* Xb     = (u16*)(w);                 // 8 MB  [4096,1024] bf16
  u16* WqkvT  = (u16*)(w + (8ull  << 20)); // 6 MB  [3072,1024] bf16 (Q|K|V transposed)
  u16* WoT    = (u16*)(w + (14ull << 20)); // 2 MB  [1024,1024] bf16
  u16* Qb     = (u16*)(w + (16ull << 20)); // 8 MB [B,H,S,64]
  u16* Kb     = (u16*)(w + (24ull << 20)); // 8 MB [B,H,S,64]
  u16* VTb    = (u16*)(w + (32ull << 20)); // 8 MB [B,H,64,S]
  u16* Ctx    = (u16*)(w + (40ull << 20)); // 8 MB [4096,1024]

  prologue<<<8192, 256, 0, stream>>>(X, Wq, Wk, Wv, Wo, Xb, WqkvT, WoT);
  gemm128<<<768, 256, 0, stream>>>(Xb, WqkvT, bq, bk, bv, Qb, Kb, VTb, 4);
  attn_kernel<<<2048, 512, 0, stream>>>(Qb, Kb, VTb, mask, Ctx);
  gemm128<<<256, 256, 0, stream>>>(Ctx, WoT, bo, bo, bo, d_out, d_out, d_out, 3);
}

// Round 8
// 237.478 us; speedup vs baseline: 1.0698x; 1.0698x over previous
//
#include <hip/hip_runtime.h>

typedef __attribute__((ext_vector_type(8))) short short8_t;  // 8 bf16 (4 VGPRs)
typedef __attribute__((ext_vector_type(4))) float float4_t;  // MFMA C/D
typedef unsigned short u16;
typedef unsigned int u32;
typedef unsigned long long u64;

// ---------- helpers ----------
__device__ inline u16 f2bf(float x) {
  union { float f; u32 u; } v; v.f = x;
  u32 r = v.u + 0x7FFFu + ((v.u >> 16) & 1u);  // round-to-nearest-even
  return (u16)(r >> 16);
}
#if __has_builtin(__builtin_amdgcn_cvt_pk_bf16_f32)
typedef __attribute__((ext_vector_type(2))) __bf16 bf162_t;
__device__ inline u32 pk2(float a, float b) {   // v_cvt_pk_bf16_f32: low=a, high=b, RNE
  union { bf162_t v; u32 u; } cv;
  cv.v = __builtin_amdgcn_cvt_pk_bf16_f32(a, b);
  return cv.u;
}
#else
__device__ inline u32 pk2(float a, float b) {
  return (u32)f2bf(a) | ((u32)f2bf(b) << 16);
}
#endif
// async global->LDS DMA, 16B per lane; lds dest = wave-uniform base + lane*16
__device__ inline void async16(const u16* g, u16* l) {
  __builtin_amdgcn_global_load_lds(
      (const __attribute__((address_space(1))) unsigned int*)g,
      (__attribute__((address_space(3))) unsigned int*)l, 16, 0, 0);
}

// ---------- fused prologue: X fp32->bf16 (blocks 0..4095), W transposes (4096..8191) ----------
__global__ __launch_bounds__(256) void prologue(const float* __restrict__ X,
                                                const float* __restrict__ Wq, const float* __restrict__ Wk,
                                                const float* __restrict__ Wv, const float* __restrict__ Wo,
                                                u16* __restrict__ Xb, u16* __restrict__ WqkvT,
                                                u16* __restrict__ WoT) {
  __shared__ float tls[32][33];
  int bid = blockIdx.x;
  if (bid < 4096) {
    int i = bid * 256 + threadIdx.x;  // one float4 per thread
    float4_t x = ((const float4_t*)X)[i];
    union { u32 u[2]; u64 ll; } o;
    o.u[0] = pk2(x[0], x[1]);
    o.u[1] = pk2(x[2], x[3]);
    ((u64*)Xb)[i] = o.ll;
  } else {
    int t = bid - 4096;
    int mat = t >> 10, tile = t & 1023;
    const float* W = (mat == 0) ? Wq : (mat == 1) ? Wk : (mat == 2) ? Wv : Wo;
    u16* WT = (mat < 3) ? WqkvT + ((size_t)mat << 20) : WoT;
    int tx = threadIdx.x & 31, ty = threadIdx.x >> 5;  // 32 x 8
    int c0 = (tile & 31) * 32, r0 = (tile >> 5) * 32;  // r0: k, c0: n
    #pragma unroll
    for (int i = 0; i < 4; ++i)
      tls[ty + i * 8][tx] = W[(r0 + ty + i * 8) * 1024 + c0 + tx];
    __syncthreads();
    #pragma unroll
    for (int i = 0; i < 4; ++i)
      WT[(size_t)(c0 + ty + i * 8) * 1024 + r0 + tx] = f2bf(tls[tx][ty + i * 8]);
  }
}

// ---------- GEMM: 128x128 C-tile, 4 waves each 64x64, BK=64 ----------
// 1D grid with L2-locality swizzle (mode 4: 16-m x n panels). LDS staged via
// global_load_lds; XOR chunk swizzle applied at global SOURCE address.
// mode 4 (fused QKV, 768 blocks): col block 0->Q(x0.125) o0 [B,H,S,64], 1->K o1,
//   2->V o2 [B,H,64,S] (transposed). mode 3 (O-proj, 256 blocks): fp32 out o0.
__global__ __launch_bounds__(256) void gemm128(const u16* __restrict__ A, const u16* __restrict__ BT,
                                               const float* __restrict__ bias0, const float* __restrict__ bias1,
                                               const float* __restrict__ bias2,
                                               void* __restrict__ o0, void* __restrict__ o1, void* __restrict__ o2,
                                               int mode) {
  __shared__ __align__(16) u16 Als[128 * 64];  // 16 KB
  __shared__ __align__(16) u16 Bls[128 * 64];  // 16 KB
  int g = blockIdx.x, m0t, n0t;
  if (mode == 4) {  // 768 blocks: panels of 16 m-tiles x 24 n-tiles
    int mh = g / 384, r = g - mh * 384;
    n0t = r >> 4;
    m0t = mh * 16 + (r & 15);
  } else {          // 256 blocks
    m0t = g & 31;
    n0t = g >> 5;
  }
  const int m0 = m0t * 128, n0 = n0t * 128;
  const int lane = threadIdx.x & 63, wave = threadIdx.x >> 6;
  const int quad = lane >> 4, c = lane & 15;
  const int wm = wave >> 1, wn = wave & 1;

  // staging: call q stages rows wave*32+q*8 .. +7 (8 rows x 8 chunks = 64 lanes)
  const int srow = lane >> 3, schunk = lane & 7;
  int soff[4];  u16 *lA[4], *lB[4];
  #pragma unroll
  for (int q = 0; q < 4; ++q) {
    int r = wave * 32 + q * 8 + srow;
    soff[q] = r * 1024 + ((schunk ^ (r & 7)) << 3);
    lA[q] = &Als[(wave * 32 + q * 8) * 64 + lane * 8];
    lB[q] = &Bls[(wave * 32 + q * 8) * 64 + lane * 8];
  }
  const u16* gA = A + (size_t)m0 * 1024;
  const u16* gB = BT + (size_t)n0 * 1024;

  int ar[2][4], br[2][4];
  #pragma unroll
  for (int ko = 0; ko < 2; ++ko) {
    #pragma unroll
    for (int i = 0; i < 4; ++i) {
      int rowa = wm * 64 + i * 16 + c;
      ar[ko][i] = rowa * 64 + (((ko * 4 + quad) ^ (rowa & 7)) << 3);
      int rowb = wn * 64 + i * 16 + c;
      br[ko][i] = rowb * 64 + (((ko * 4 + quad) ^ (rowb & 7)) << 3);
    }
  }

  float4_t acc[4][4] = {};
  for (int k0 = 0; k0 < 1024; k0 += 64) {
    #pragma unroll
    for (int q = 0; q < 4; ++q) async16(gA + soff[q] + k0, lA[q]);
    #pragma unroll
    for (int q = 0; q < 4; ++q) async16(gB + soff[q] + k0, lB[q]);
    __syncthreads();
    #pragma unroll
    for (int ko = 0; ko < 2; ++ko) {
      short8_t af[4], bfr[4];
      #pragma unroll
      for (int i = 0; i < 4; ++i) af[i] = *(const short8_t*)&Als[ar[ko][i]];
      #pragma unroll
      for (int j = 0; j < 4; ++j) bfr[j] = *(const short8_t*)&Bls[br[ko][j]];
      #pragma unroll
      for (int i = 0; i < 4; ++i)
        #pragma unroll
        for (int j = 0; j < 4; ++j)
          acc[i][j] = __builtin_amdgcn_mfma_f32_16x16x32_bf16(af[i], bfr[j], acc[i][j], 0, 0, 0);
    }
    __syncthreads();
  }

  const int mrow = m0 + wm * 64, ncol = n0 + wn * 64;
  if (mode == 3) {
    float* o = (float*)o0;
    #pragma unroll
    for (int i = 0; i < 4; ++i) {
      #pragma unroll
      for (int j = 0; j < 4; ++j) {
        int colb = ncol + j * 16 + c;
        float bv = bias0[colb];
        int rowb = mrow + i * 16 + quad * 4;
        #pragma unroll
        for (int r = 0; r < 4; ++r)
          o[(size_t)(rowb + r) * 1024 + colb] = acc[i][j][r] + bv;
      }
    }
  } else {
    #pragma unroll
    for (int j = 0; j < 4; ++j) {
      int colb = ncol + j * 16 + c;     // 0..3071
      int which = colb >> 10;           // 0:Q 1:K 2:V (uniform per j)
      int n1 = colb & 1023, h = n1 >> 6, d = n1 & 63;
      const float* bp = (which == 0) ? bias0 : (which == 1 ? bias1 : bias2);
      float bv = bp[n1];
      #pragma unroll
      for (int i = 0; i < 4; ++i) {
        int rowb = mrow + i * 16 + quad * 4;
        int b = rowb >> 11, s = rowb & 2047;
        if (which == 2) {
          u16* o = (u16*)o2 + (((size_t)(b * 16 + h) * 64 + d) * 2048 + s);
          union { u32 u[2]; u64 ll; } ov;
          ov.u[0] = pk2(acc[i][j][0] + bv, acc[i][j][1] + bv);
          ov.u[1] = pk2(acc[i][j][2] + bv, acc[i][j][3] + bv);
          *(u64*)o = ov.ll;
        } else {
          float sc = (which == 0) ? 0.125f : 1.0f;
          u16* o = (u16*)((which == 0) ? o0 : o1);
          #pragma unroll
          for (int r = 0; r < 4; ++r)
            o[(((size_t)(b * 16 + h) * 2048 + (s + r)) << 6) + d] = f2bf((acc[i][j][r] + bv) * sc);
        }
      }
    }
  }
}

// P^T C-layout -> 16x16x32 B-operand layout via packed-bf16 shuffles
__device__ inline short8_t p_to_b32(const float* p, int quad, int c) {
  u32 pk0[2] = {pk2(p[0], p[1]), pk2(p[2], p[3])};
  u32 pk1[2] = {pk2(p[4], p[5]), pk2(p[6], p[7])};
  int base = ((quad & 1) * 2) * 16 + c;
  union { u32 u[4]; short8_t v; } pf;
  #pragma unroll
  for (int x = 0; x < 4; ++x) {
    int src = base + ((x >> 1) << 4);
    int v0 = __shfl((int)pk0[x & 1], src);
    int v1 = __shfl((int)pk1[x & 1], src);
    pf.u[x] = (quad < 2) ? (u32)v0 : (u32)v1;
  }
  return pf.v;
}

// ---------- flash attention (prefill): 128-query tile per block, K/V staged in LDS ----------
// Q,K: [B,H,S,64] bf16 (Q pre-scaled 1/8); VT: [B,H,64,S]; ctx: [B,S,1024] bf16.
// Grid 512 x 256: block = (bh, 128-query tile qt). bh = (g&7)*4+((g>>3)&3) (XCD L2
// affinity for K/V); qt = u5<8 ? u5 : 23-u5 so qt(g)+qt(g+256)=15 (balanced CU load).
// 4 waves each own 32 queries (halves A/B); per K-tile of 128 keys: stage K (128x64)
// and V^T (64x128) into 32KB LDS via global_load_lds w/ XOR source swizzle (frag
// ds_read_b128 -> 2-way conflict = free). Each staged byte feeds all 4 waves: L2
// traffic /4 vs fragment-direct, 64 MFMA per wave-iter. Fixed-base softmax (no
// running max; masked -> exp2(-50)=0); causal select only on the diagonal tile.
// No K-split -> no LDS combine; l reduced across quads once at the end.
__global__ __launch_bounds__(256, 2) void attn_kernel(const u16* __restrict__ Q, const u16* __restrict__ K,
                                                      const u16* __restrict__ VT, const float* __restrict__ mask,
                                                      u16* __restrict__ ctx) {
  __shared__ __align__(16) u16 Kls[128 * 64];  // 16 KB [key][d]
  __shared__ __align__(16) u16 Vls[64 * 128];  // 16 KB [d][key]
  const float C1 = 10000.0f * 1.4426950408889634f;
  const float LOG2E = 1.4426950408889634f;
  int w = threadIdx.x >> 6, lane = threadIdx.x & 63;
  int quad = lane >> 4, c = lane & 15;
  int g = blockIdx.x;
  int bh = (g & 7) * 4 + ((g >> 3) & 3);
  int u5 = g >> 5;                        // 0..15
  int qt = (u5 < 8) ? u5 : 23 - u5;       // complementary pairing across the grid
  int b = bh >> 4, h = bh & 15;
  const u16* Kp = K + ((size_t)bh << 17);
  const u16* Vp = VT + ((size_t)bh << 17);
  const float* mp = mask + (b << 11);
  int q0 = qt * 128 + w * 32;

  // Q^T B-operand fragments (two 16-query halves)
  const u16* Qp = Q + (((size_t)bh * 2048 + q0 + c) << 6) + quad * 8;
  short8_t qA0 = *(const short8_t*)(Qp);
  short8_t qA1 = *(const short8_t*)(Qp + 32);
  short8_t qB0 = *(const short8_t*)(Qp + 1024);
  short8_t qB1 = *(const short8_t*)(Qp + 1024 + 32);

  // staging geometry: K tile = 128 rows x 8 chunks(16B); wave w stages rows w*32..+31
  const u16* gK[4]; u16* dK[4];
  {
    int srow = lane >> 3, schunk = lane & 7;
    #pragma unroll
    for (int i = 0; i < 4; ++i) {
      int R = w * 32 + i * 8 + srow;
      gK[i] = Kp + R * 64 + ((schunk ^ (R & 7)) << 3);
      dK[i] = &Kls[(w * 32 + i * 8) * 64 + lane * 8];
    }
  }
  // V tile = 64 rows x 16 chunks(16B); wave w stages d-rows w*16..+15
  const u16* gV[4]; u16* dV[4];
  {
    int srow = lane >> 4, schunk = lane & 15;
    #pragma unroll
    for (int i = 0; i < 4; ++i) {
      int d = w * 16 + i * 4 + srow;
      gV[i] = Vp + (size_t)d * 2048 + ((schunk ^ (d & 15)) << 3);
      dV[i] = &Vls[(w * 16 + i * 4) * 128 + lane * 8];
    }
  }

  // fragment read offsets (u16) with matching swizzle
  int koff[8][2];
  #pragma unroll
  for (int kg = 0; kg < 8; ++kg) {
    int r = kg * 16 + c;
    #pragma unroll
    for (int ko = 0; ko < 2; ++ko)
      koff[kg][ko] = r * 64 + (((ko * 4 + quad) ^ (r & 7)) << 3);
  }
  int voff[4][4];
  #pragma unroll
  for (int dblk = 0; dblk < 4; ++dblk) {
    int d = dblk * 16 + c;
    #pragma unroll
    for (int kc = 0; kc < 4; ++kc)
      voff[dblk][kc] = d * 128 + (((kc * 4 + quad) ^ (d & 15)) << 3);
  }

  int ke[8];
  #pragma unroll
  for (int e = 0; e < 8; ++e) ke[e] = ((e >> 2) << 4) + quad * 4 + (e & 3);
  int thrA = w * 32 + c, thrB = w * 32 + 16 + c;  // causal thresholds within diag tile

  float4_t OA[4] = {}, OB[4] = {};
  float lA = 0.0f, lB = 0.0f;

  for (int t = 0; t <= qt; ++t) {
    int kb = t << 7;  // key base
    #pragma unroll
    for (int i = 0; i < 4; ++i) async16(gK[i] + (size_t)kb * 64, dK[i]);
    #pragma unroll
    for (int i = 0; i < 4; ++i) async16(gV[i] + kb, dV[i]);
    __syncthreads();
    // ---- S^T = K_tile @ Q^T (32 MFMA) ----
    float4_t sA[8], sB[8];
    #pragma unroll
    for (int kg = 0; kg < 8; ++kg) {
      short8_t k0 = *(const short8_t*)&Kls[koff[kg][0]];
      short8_t k1 = *(const short8_t*)&Kls[koff[kg][1]];
      float4_t a = {}, bb = {};
      a = __builtin_amdgcn_mfma_f32_16x16x32_bf16(k0, qA0, a, 0, 0, 0);
      a = __builtin_amdgcn_mfma_f32_16x16x32_bf16(k1, qA1, a, 0, 0, 0);
      bb = __builtin_amdgcn_mfma_f32_16x16x32_bf16(k0, qB0, bb, 0, 0, 0);
      bb = __builtin_amdgcn_mfma_f32_16x16x32_bf16(k1, qB1, bb, 0, 0, 0);
      sA[kg] = a; sB[kg] = bb;
    }
    // ---- masks + fixed-base softmax + C->B transform ----
    float4_t mpl[8];
    #pragma unroll
    for (int kg = 0; kg < 8; ++kg)
      mpl[kg] = (*(const float4_t*)(mp + kb + kg * 16 + quad * 4) - 1.0f) * C1;
    bool diag = (t == qt);
    short8_t pfA[4], pfB[4];
    #pragma unroll
    for (int kc = 0; kc < 4; ++kc) {
      float pA[8], pB[8];
      #pragma unroll
      for (int e = 0; e < 8; ++e) {
        int kg = kc * 2 + (e >> 2);
        float ml = mpl[kg][e & 3];
        pA[e] = __builtin_fmaf(sA[kg][e & 3], LOG2E, ml);
        pB[e] = __builtin_fmaf(sB[kg][e & 3], LOG2E, ml);
      }
      if (diag) {
        #pragma unroll
        for (int e = 0; e < 8; ++e) {
          int ko2 = kc * 32 + ke[e];
          pA[e] = (ko2 > thrA) ? -50.0f : pA[e];
          pB[e] = (ko2 > thrB) ? -50.0f : pB[e];
        }
      }
      #pragma unroll
      for (int e = 0; e < 8; ++e) {
        float a = exp2f(pA[e]); pA[e] = a; lA += a;
        float bb = exp2f(pB[e]); pB[e] = bb; lB += bb;
      }
      pfA[kc] = p_to_b32(pA, quad, c);
      pfB[kc] = p_to_b32(pB, quad, c);
    }
    // ---- ctx^T += V^T_tile @ P^T (32 MFMA) ----
    #pragma unroll
    for (int dblk = 0; dblk < 4; ++dblk) {
      #pragma unroll
      for (int kc = 0; kc < 4; ++kc) {
        short8_t vf = *(const short8_t*)&Vls[voff[dblk][kc]];
        OA[dblk] = __builtin_amdgcn_mfma_f32_16x16x32_bf16(vf, pfA[kc], OA[dblk], 0, 0, 0);
        OB[dblk] = __builtin_amdgcn_mfma_f32_16x16x32_bf16(vf, pfB[kc], OB[dblk], 0, 0, 0);
      }
    }
    __syncthreads();  // protect LDS before next tile's DMA
  }
  // ---- epilogue: reduce l across quads, normalize, store ----
  lA += __shfl_xor(lA, 16); lA += __shfl_xor(lA, 32);
  lB += __shfl_xor(lB, 16); lB += __shfl_xor(lB, 32);
  float rA = 1.0f / lA, rB = 1.0f / lB;
  u16* opA = ctx + ((size_t)(b * 2048 + q0 + c) * 1024 + h * 64 + quad * 4);
  u16* opB = ctx + ((size_t)(b * 2048 + q0 + 16 + c) * 1024 + h * 64 + quad * 4);
  #pragma unroll
  for (int dblk = 0; dblk < 4; ++dblk) {
    union { u32 uu[2]; u64 ll; } ov;
    ov.uu[0] = pk2(OA[dblk][0] * rA, OA[dblk][1] * rA);
    ov.uu[1] = pk2(OA[dblk][2] * rA, OA[dblk][3] * rA);
    *(u64*)(opA + dblk * 16) = ov.ll;
    ov.uu[0] = pk2(OB[dblk][0] * rB, OB[dblk][1] * rB);
    ov.uu[1] = pk2(OB[dblk][2] * rB, OB[dblk][3] * rB);
    *(u64*)(opB + dblk * 16) = ov.ll;
  }
}

// ---------- launch ----------
extern "C" void kernel_launch(void* const* d_in, const int* in_sizes, int n_in,
                              void* d_out, int out_size, void* d_ws, size_t ws_size,
                              hipStream_t stream) {
  const float* X    = (const float*)d_in[0];
  const float* mask = (const float*)d_in[1];
  const float* Wq   = (const float*)d_in[2];
  const float* bq   = (const float*)d_in[3];
  const float* Wk   = (const float*)d_in[4];
  const float* bk   = (const float*)d_in[5];
  const float* Wv   = (const float*)d_in[6];
  const float* bv   = (const float*)d_in[7];
  const float* Wo   = (const float*)d_in[8];
  const float* bo   = (const float*)d_in[9];

  char* w = (char*)d_ws;
  u16* Xb     = (u16*)(w);                 // 8 MB  [4096,1024] bf16
  u16* WqkvT  = (u16*)(w + (8ull  << 20)); // 6 MB  [3072,1024] bf16 (Q|K|V transposed)
  u16* WoT    = (u16*)(w + (14ull << 20)); // 2 MB  [1024,1024] bf16
  u16* Qb     = (u16*)(w + (16ull << 20)); // 8 MB [B,H,S,64]
  u16* Kb     = (u16*)(w + (24ull << 20)); // 8 MB [B,H,S,64]
  u16* VTb    = (u16*)(w + (32ull << 20)); // 8 MB [B,H,64,S]
  u16* Ctx    = (u16*)(w + (40ull << 20)); // 8 MB [4096,1024]

  prologue<<<8192, 256, 0, stream>>>(X, Wq, Wk, Wv, Wo, Xb, WqkvT, WoT);
  gemm128<<<768, 256, 0, stream>>>(Xb, WqkvT, bq, bk, bv, Qb, Kb, VTb, 4);
  attn_kernel<<<512, 256, 0, stream>>>(Qb, Kb, VTb, mask, Ctx);
  gemm128<<<256, 256, 0, stream>>>(Ctx, WoT, bo, bo, bo, d_out, d_out, d_out, 3);
}

// Round 9
// 225.085 us; speedup vs baseline: 1.1287x; 1.0551x over previous
//
#include <hip/hip_runtime.h>

typedef __attribute__((ext_vector_type(8))) short short8_t;  // 8 bf16 (4 VGPRs)
typedef __attribute__((ext_vector_type(4))) float float4_t;  // MFMA C/D
typedef unsigned short u16;
typedef unsigned int u32;
typedef unsigned long long u64;

// ---------- helpers ----------
__device__ inline u16 f2bf(float x) {
  union { float f; u32 u; } v; v.f = x;
  u32 r = v.u + 0x7FFFu + ((v.u >> 16) & 1u);  // round-to-nearest-even
  return (u16)(r >> 16);
}
#if __has_builtin(__builtin_amdgcn_cvt_pk_bf16_f32)
typedef __attribute__((ext_vector_type(2))) __bf16 bf162_t;
__device__ inline u32 pk2(float a, float b) {   // v_cvt_pk_bf16_f32: low=a, high=b, RNE
  union { bf162_t v; u32 u; } cv;
  cv.v = __builtin_amdgcn_cvt_pk_bf16_f32(a, b);
  return cv.u;
}
#else
__device__ inline u32 pk2(float a, float b) {
  return (u32)f2bf(a) | ((u32)f2bf(b) << 16);
}
#endif
// async global->LDS DMA, 16B per lane; lds dest = wave-uniform base + lane*16
__device__ inline void async16(const u16* g, u16* l) {
  __builtin_amdgcn_global_load_lds(
      (const __attribute__((address_space(1))) unsigned int*)g,
      (__attribute__((address_space(3))) unsigned int*)l, 16, 0, 0);
}

// ---------- fused prologue: X fp32->bf16 (blocks 0..4095), W transposes (4096..8191) ----------
__global__ __launch_bounds__(256) void prologue(const float* __restrict__ X,
                                                const float* __restrict__ Wq, const float* __restrict__ Wk,
                                                const float* __restrict__ Wv, const float* __restrict__ Wo,
                                                u16* __restrict__ Xb, u16* __restrict__ WqkvT,
                                                u16* __restrict__ WoT) {
  __shared__ float tls[32][33];
  int bid = blockIdx.x;
  if (bid < 4096) {
    int i = bid * 256 + threadIdx.x;  // one float4 per thread
    float4_t x = ((const float4_t*)X)[i];
    union { u32 u[2]; u64 ll; } o;
    o.u[0] = pk2(x[0], x[1]);
    o.u[1] = pk2(x[2], x[3]);
    ((u64*)Xb)[i] = o.ll;
  } else {
    int t = bid - 4096;
    int mat = t >> 10, tile = t & 1023;
    const float* W = (mat == 0) ? Wq : (mat == 1) ? Wk : (mat == 2) ? Wv : Wo;
    u16* WT = (mat < 3) ? WqkvT + ((size_t)mat << 20) : WoT;
    int tx = threadIdx.x & 31, ty = threadIdx.x >> 5;  // 32 x 8
    int c0 = (tile & 31) * 32, r0 = (tile >> 5) * 32;  // r0: k, c0: n
    #pragma unroll
    for (int i = 0; i < 4; ++i)
      tls[ty + i * 8][tx] = W[(r0 + ty + i * 8) * 1024 + c0 + tx];
    __syncthreads();
    #pragma unroll
    for (int i = 0; i < 4; ++i)
      WT[(size_t)(c0 + ty + i * 8) * 1024 + r0 + tx] = f2bf(tls[tx][ty + i * 8]);
  }
}

// ---------- GEMM: 128x128 C-tile, 4 waves each 64x64, BK=64 ----------
// 1D grid with L2-locality swizzle (mode 4: 16-m x n panels). LDS staged via
// global_load_lds; XOR chunk swizzle applied at global SOURCE address.
// mode 4 (fused QKV, 768 blocks): col block 0->Q(x0.125) o0 [B,H,S,64], 1->K o1,
//   2->V o2 [B,H,64,S] (transposed). mode 3 (O-proj, 256 blocks): fp32 out o0.
__global__ __launch_bounds__(256) void gemm128(const u16* __restrict__ A, const u16* __restrict__ BT,
                                               const float* __restrict__ bias0, const float* __restrict__ bias1,
                                               const float* __restrict__ bias2,
                                               void* __restrict__ o0, void* __restrict__ o1, void* __restrict__ o2,
                                               int mode) {
  __shared__ __align__(16) u16 Als[128 * 64];  // 16 KB
  __shared__ __align__(16) u16 Bls[128 * 64];  // 16 KB
  int g = blockIdx.x, m0t, n0t;
  if (mode == 4) {  // 768 blocks: panels of 16 m-tiles x 24 n-tiles
    int mh = g / 384, r = g - mh * 384;
    n0t = r >> 4;
    m0t = mh * 16 + (r & 15);
  } else {          // 256 blocks
    m0t = g & 31;
    n0t = g >> 5;
  }
  const int m0 = m0t * 128, n0 = n0t * 128;
  const int lane = threadIdx.x & 63, wave = threadIdx.x >> 6;
  const int quad = lane >> 4, c = lane & 15;
  const int wm = wave >> 1, wn = wave & 1;

  // staging: call q stages rows wave*32+q*8 .. +7 (8 rows x 8 chunks = 64 lanes)
  const int srow = lane >> 3, schunk = lane & 7;
  int soff[4];  u16 *lA[4], *lB[4];
  #pragma unroll
  for (int q = 0; q < 4; ++q) {
    int r = wave * 32 + q * 8 + srow;
    soff[q] = r * 1024 + ((schunk ^ (r & 7)) << 3);
    lA[q] = &Als[(wave * 32 + q * 8) * 64 + lane * 8];
    lB[q] = &Bls[(wave * 32 + q * 8) * 64 + lane * 8];
  }
  const u16* gA = A + (size_t)m0 * 1024;
  const u16* gB = BT + (size_t)n0 * 1024;

  int ar[2][4], br[2][4];
  #pragma unroll
  for (int ko = 0; ko < 2; ++ko) {
    #pragma unroll
    for (int i = 0; i < 4; ++i) {
      int rowa = wm * 64 + i * 16 + c;
      ar[ko][i] = rowa * 64 + (((ko * 4 + quad) ^ (rowa & 7)) << 3);
      int rowb = wn * 64 + i * 16 + c;
      br[ko][i] = rowb * 64 + (((ko * 4 + quad) ^ (rowb & 7)) << 3);
    }
  }

  float4_t acc[4][4] = {};
  for (int k0 = 0; k0 < 1024; k0 += 64) {
    #pragma unroll
    for (int q = 0; q < 4; ++q) async16(gA + soff[q] + k0, lA[q]);
    #pragma unroll
    for (int q = 0; q < 4; ++q) async16(gB + soff[q] + k0, lB[q]);
    __syncthreads();
    #pragma unroll
    for (int ko = 0; ko < 2; ++ko) {
      short8_t af[4], bfr[4];
      #pragma unroll
      for (int i = 0; i < 4; ++i) af[i] = *(const short8_t*)&Als[ar[ko][i]];
      #pragma unroll
      for (int j = 0; j < 4; ++j) bfr[j] = *(const short8_t*)&Bls[br[ko][j]];
      #pragma unroll
      for (int i = 0; i < 4; ++i)
        #pragma unroll
        for (int j = 0; j < 4; ++j)
          acc[i][j] = __builtin_amdgcn_mfma_f32_16x16x32_bf16(af[i], bfr[j], acc[i][j], 0, 0, 0);
    }
    __syncthreads();
  }

  const int mrow = m0 + wm * 64, ncol = n0 + wn * 64;
  if (mode == 3) {
    float* o = (float*)o0;
    #pragma unroll
    for (int i = 0; i < 4; ++i) {
      #pragma unroll
      for (int j = 0; j < 4; ++j) {
        int colb = ncol + j * 16 + c;
        float bv = bias0[colb];
        int rowb = mrow + i * 16 + quad * 4;
        #pragma unroll
        for (int r = 0; r < 4; ++r)
          o[(size_t)(rowb + r) * 1024 + colb] = acc[i][j][r] + bv;
      }
    }
  } else {
    #pragma unroll
    for (int j = 0; j < 4; ++j) {
      int colb = ncol + j * 16 + c;     // 0..3071
      int which = colb >> 10;           // 0:Q 1:K 2:V (uniform per j)
      int n1 = colb & 1023, h = n1 >> 6, d = n1 & 63;
      const float* bp = (which == 0) ? bias0 : (which == 1 ? bias1 : bias2);
      float bv = bp[n1];
      #pragma unroll
      for (int i = 0; i < 4; ++i) {
        int rowb = mrow + i * 16 + quad * 4;
        int b = rowb >> 11, s = rowb & 2047;
        if (which == 2) {
          u16* o = (u16*)o2 + (((size_t)(b * 16 + h) * 64 + d) * 2048 + s);
          union { u32 u[2]; u64 ll; } ov;
          ov.u[0] = pk2(acc[i][j][0] + bv, acc[i][j][1] + bv);
          ov.u[1] = pk2(acc[i][j][2] + bv, acc[i][j][3] + bv);
          *(u64*)o = ov.ll;
        } else {
          float sc = (which == 0) ? 0.125f : 1.0f;
          u16* o = (u16*)((which == 0) ? o0 : o1);
          #pragma unroll
          for (int r = 0; r < 4; ++r)
            o[(((size_t)(b * 16 + h) * 2048 + (s + r)) << 6) + d] = f2bf((acc[i][j][r] + bv) * sc);
        }
      }
    }
  }
}

// P^T C-layout -> 16x16x32 B-operand layout via packed-bf16 shuffles
__device__ inline short8_t p_to_b32(const float* p, int quad, int c) {
  u32 pk0[2] = {pk2(p[0], p[1]), pk2(p[2], p[3])};
  u32 pk1[2] = {pk2(p[4], p[5]), pk2(p[6], p[7])};
  int base = ((quad & 1) * 2) * 16 + c;
  union { u32 u[4]; short8_t v; } pf;
  #pragma unroll
  for (int x = 0; x < 4; ++x) {
    int src = base + ((x >> 1) << 4);
    int v0 = __shfl((int)pk0[x & 1], src);
    int v1 = __shfl((int)pk1[x & 1], src);
    pf.u[x] = (quad < 2) ? (u32)v0 : (u32)v1;
  }
  return pf.v;
}

// ---------- flash attention (prefill): 128-query tile per block, K/V staged in LDS ----------
// Q,K: [B,H,S,64] bf16 (Q pre-scaled 1/8); VT: [B,H,64,S]; ctx: [B,S,1024] bf16.
// Grid 512 x 256: block = (bh, 128-query tile qt). bh = (g&7)*4+((g>>3)&3) (XCD L2
// affinity); qt = u5<8 ? 15-u5 : u5-8 -> HEAVY tiles dispatch FIRST and co-resident
// pairs (g, g+256) sum to 15 tiles (uniform CU load; r8's light-first mapping left
// heavy blocks running alone -> 12% occupancy tail).
// Pipelined staging (fixes r8's naked DMA->barrier drain, ~4.5k cyc/tile): tile t+1's
// K/V quarters are loaded into VGPRs *during* tile t's compute (latency hidden under
// ~1.2k cyc of MFMA+softmax), then ds_written to LDS at the top of the next iteration.
// Barriers only wait on loads that have had a full compute phase to land.
// Fixed-base softmax (no running max; masked -> exp2(-50)=0); causal select only on
// the diagonal tile. l reduced across quads once at the end.
__global__ __launch_bounds__(256, 2) void attn_kernel(const u16* __restrict__ Q, const u16* __restrict__ K,
                                                      const u16* __restrict__ VT, const float* __restrict__ mask,
                                                      u16* __restrict__ ctx) {
  __shared__ __align__(16) u16 Kls[128 * 64];  // 16 KB [key][d], chunk-swizzled
  __shared__ __align__(16) u16 Vls[64 * 128];  // 16 KB [d][key], chunk-swizzled
  const float C1 = 10000.0f * 1.4426950408889634f;
  const float LOG2E = 1.4426950408889634f;
  int w = threadIdx.x >> 6, lane = threadIdx.x & 63;
  int quad = lane >> 4, c = lane & 15;
  int g = blockIdx.x;
  int bh = (g & 7) * 4 + ((g >> 3) & 3);
  int u5 = g >> 5;                           // 0..15
  int qt = (u5 < 8) ? (15 - u5) : (u5 - 8);  // heavy first; pairs (g,g+256) sum to 15
  int b = bh >> 4, h = bh & 15;
  const u16* Kp = K + ((size_t)bh << 17);
  const u16* Vp = VT + ((size_t)bh << 17);
  const float* mp = mask + (b << 11);
  int q0 = qt * 128 + w * 32;

  // Q^T B-operand fragments (two 16-query halves)
  const u16* Qp = Q + (((size_t)bh * 2048 + q0 + c) << 6) + quad * 8;
  short8_t qA0 = *(const short8_t*)(Qp);
  short8_t qA1 = *(const short8_t*)(Qp + 32);
  short8_t qB0 = *(const short8_t*)(Qp + 1024);
  short8_t qB1 = *(const short8_t*)(Qp + 1024 + 32);

  // staging geometry: K tile = 128 rows x 8 chunks(16B); wave w stages rows w*32..+31
  const u16* gK[4]; int dK[4];
  {
    int srow = lane >> 3, schunk = lane & 7;
    #pragma unroll
    for (int i = 0; i < 4; ++i) {
      int R = w * 32 + i * 8 + srow;
      gK[i] = Kp + R * 64 + ((schunk ^ (R & 7)) << 3);
      dK[i] = (w * 32 + i * 8) * 64 + lane * 8;
    }
  }
  // V tile = 64 rows x 16 chunks(16B); wave w stages d-rows w*16..+15
  const u16* gV[4]; int dV[4];
  {
    int srow = lane >> 4, schunk = lane & 15;
    #pragma unroll
    for (int i = 0; i < 4; ++i) {
      int d = w * 16 + i * 4 + srow;
      gV[i] = Vp + (size_t)d * 2048 + ((schunk ^ (d & 15)) << 3);
      dV[i] = (w * 16 + i * 4) * 128 + lane * 8;
    }
  }

  // fragment read offsets (u16) with matching swizzle
  int koff[8][2];
  #pragma unroll
  for (int kg = 0; kg < 8; ++kg) {
    int r = kg * 16 + c;
    #pragma unroll
    for (int ko = 0; ko < 2; ++ko)
      koff[kg][ko] = r * 64 + (((ko * 4 + quad) ^ (r & 7)) << 3);
  }
  int voff[4][4];
  #pragma unroll
  for (int dblk = 0; dblk < 4; ++dblk) {
    int d = dblk * 16 + c;
    #pragma unroll
    for (int kc = 0; kc < 4; ++kc)
      voff[dblk][kc] = d * 128 + (((kc * 4 + quad) ^ (d & 15)) << 3);
  }

  int ke[8];
  #pragma unroll
  for (int e = 0; e < 8; ++e) ke[e] = ((e >> 2) << 4) + quad * 4 + (e & 3);
  int thrA = w * 32 + c, thrB = w * 32 + 16 + c;  // causal thresholds within diag tile

  float4_t OA[4] = {}, OB[4] = {};
  float lA = 0.0f, lB = 0.0f;

  // prefetch tile 0 into VGPRs
  short8_t kreg[4], vreg[4];
  #pragma unroll
  for (int i = 0; i < 4; ++i) kreg[i] = *(const short8_t*)(gK[i]);
  #pragma unroll
  for (int i = 0; i < 4; ++i) vreg[i] = *(const short8_t*)(gV[i]);

  for (int t = 0; t <= qt; ++t) {
    int kb = t << 7;  // key base
    // ---- commit prefetched tile t to LDS ----
    #pragma unroll
    for (int i = 0; i < 4; ++i) *(short8_t*)&Kls[dK[i]] = kreg[i];
    #pragma unroll
    for (int i = 0; i < 4; ++i) *(short8_t*)&Vls[dV[i]] = vreg[i];
    __syncthreads();
    // ---- issue tile t+1 loads now; latency hides under this tile's compute ----
    if (t < qt) {
      int kb2 = (t + 1) << 7;
      #pragma unroll
      for (int i = 0; i < 4; ++i) kreg[i] = *(const short8_t*)(gK[i] + (size_t)kb2 * 64);
      #pragma unroll
      for (int i = 0; i < 4; ++i) vreg[i] = *(const short8_t*)(gV[i] + kb2);
    }
    // ---- S^T = K_tile @ Q^T (32 MFMA) ----
    float4_t sA[8], sB[8];
    #pragma unroll
    for (int kg = 0; kg < 8; ++kg) {
      short8_t k0 = *(const short8_t*)&Kls[koff[kg][0]];
      short8_t k1 = *(const short8_t*)&Kls[koff[kg][1]];
      float4_t a = {}, bb = {};
      a = __builtin_amdgcn_mfma_f32_16x16x32_bf16(k0, qA0, a, 0, 0, 0);
      a = __builtin_amdgcn_mfma_f32_16x16x32_bf16(k1, qA1, a, 0, 0, 0);
      bb = __builtin_amdgcn_mfma_f32_16x16x32_bf16(k0, qB0, bb, 0, 0, 0);
      bb = __builtin_amdgcn_mfma_f32_16x16x32_bf16(k1, qB1, bb, 0, 0, 0);
      sA[kg] = a; sB[kg] = bb;
    }
    // ---- masks + fixed-base softmax + C->B transform ----
    float4_t mpl[8];
    #pragma unroll
    for (int kg = 0; kg < 8; ++kg)
      mpl[kg] = (*(const float4_t*)(mp + kb + kg * 16 + quad * 4) - 1.0f) * C1;
    bool diag = (t == qt);
    short8_t pfA[4], pfB[4];
    #pragma unroll
    for (int kc = 0; kc < 4; ++kc) {
      float pA[8], pB[8];
      #pragma unroll
      for (int e = 0; e < 8; ++e) {
        int kg = kc * 2 + (e >> 2);
        float ml = mpl[kg][e & 3];
        pA[e] = __builtin_fmaf(sA[kg][e & 3], LOG2E, ml);
        pB[e] = __builtin_fmaf(sB[kg][e & 3], LOG2E, ml);
      }
      if (diag) {
        #pragma unroll
        for (int e = 0; e < 8; ++e) {
          int ko2 = kc * 32 + ke[e];
          pA[e] = (ko2 > thrA) ? -50.0f : pA[e];
          pB[e] = (ko2 > thrB) ? -50.0f : pB[e];
        }
      }
      #pragma unroll
      for (int e = 0; e < 8; ++e) {
        float a = exp2f(pA[e]); pA[e] = a; lA += a;
        float bb = exp2f(pB[e]); pB[e] = bb; lB += bb;
      }
      pfA[kc] = p_to_b32(pA, quad, c);
      pfB[kc] = p_to_b32(pB, quad, c);
    }
    // ---- ctx^T += V^T_tile @ P^T (32 MFMA) ----
    #pragma unroll
    for (int dblk = 0; dblk < 4; ++dblk) {
      #pragma unroll
      for (int kc = 0; kc < 4; ++kc) {
        short8_t vf = *(const short8_t*)&Vls[voff[dblk][kc]];
        OA[dblk] = __builtin_amdgcn_mfma_f32_16x16x32_bf16(vf, pfA[kc], OA[dblk], 0, 0, 0);
        OB[dblk] = __builtin_amdgcn_mfma_f32_16x16x32_bf16(vf, pfB[kc], OB[dblk], 0, 0, 0);
      }
    }
    __syncthreads();  // all waves done reading LDS before next tile's ds_write
  }
  // ---- epilogue: reduce l across quads, normalize, store ----
  lA += __shfl_xor(lA, 16); lA += __shfl_xor(lA, 32);
  lB += __shfl_xor(lB, 16); lB += __shfl_xor(lB, 32);
  float rA = 1.0f / lA, rB = 1.0f / lB;
  u16* opA = ctx + ((size_t)(b * 2048 + q0 + c) * 1024 + h * 64 + quad * 4);
  u16* opB = ctx + ((size_t)(b * 2048 + q0 + 16 + c) * 1024 + h * 64 + quad * 4);
  #pragma unroll
  for (int dblk = 0; dblk < 4; ++dblk) {
    union { u32 uu[2]; u64 ll; } ov;
    ov.uu[0] = pk2(OA[dblk][0] * rA, OA[dblk][1] * rA);
    ov.uu[1] = pk2(OA[dblk][2] * rA, OA[dblk][3] * rA);
    *(u64*)(opA + dblk * 16) = ov.ll;
    ov.uu[0] = pk2(OB[dblk][0] * rB, OB[dblk][1] * rB);
    ov.uu[1] = pk2(OB[dblk][2] * rB, OB[dblk][3] * rB);
    *(u64*)(opB + dblk * 16) = ov.ll;
  }
}

// ---------- launch ----------
extern "C" void kernel_launch(void* const* d_in, const int* in_sizes, int n_in,
                              void* d_out, int out_size, void* d_ws, size_t ws_size,
                              hipStream_t stream) {
  const float* X    = (const float*)d_in[0];
  const float* mask = (const float*)d_in[1];
  const float* Wq   = (const float*)d_in[2];
  const float* bq   = (const float*)d_in[3];
  const float* Wk   = (const float*)d_in[4];
  const float* bk   = (const float*)d_in[5];
  const float* Wv   = (const float*)d_in[6];
  const float* bv   = (const float*)d_in[7];
  const float* Wo   = (const float*)d_in[8];
  const float* bo   = (const float*)d_in[9];

  char* w = (char*)d_ws;
  u16* Xb     = (u16*)(w);                 // 8 MB  [4096,1024] bf16
  u16* WqkvT  = (u16*)(w + (8ull  << 20)); // 6 MB  [3072,1024] bf16 (Q|K|V transposed)
  u16* WoT    = (u16*)(w + (14ull << 20)); // 2 MB  [1024,1024] bf16
  u16* Qb     = (u16*)(w + (16ull << 20)); // 8 MB [B,H,S,64]
  u16* Kb     = (u16*)(w + (24ull << 20)); // 8 MB [B,H,S,64]
  u16* VTb    = (u16*)(w + (32ull << 20)); // 8 MB [B,H,64,S]
  u16* Ctx    = (u16*)(w + (40ull << 20)); // 8 MB [4096,1024]

  prologue<<<8192, 256, 0, stream>>>(X, Wq, Wk, Wv, Wo, Xb, WqkvT, WoT);
  gemm128<<<768, 256, 0, stream>>>(Xb, WqkvT, bq, bk, bv, Qb, Kb, VTb, 4);
  attn_kernel<<<512, 256, 0, stream>>>(Qb, Kb, VTb, mask, Ctx);
  gemm128<<<256, 256, 0, stream>>>(Ctx, WoT, bo, bo, bo, d_out, d_out, d_out, 3);
}

// Round 10
// 207.633 us; speedup vs baseline: 1.2236x; 1.0841x over previous
//
#include <hip/hip_runtime.h>

typedef __attribute__((ext_vector_type(8))) short short8_t;  // 8 bf16 (4 VGPRs)
typedef __attribute__((ext_vector_type(4))) float float4_t;  // MFMA C/D
typedef unsigned short u16;
typedef unsigned int u32;
typedef unsigned long long u64;

// ---------- helpers ----------
__device__ inline u16 f2bf(float x) {
  union { float f; u32 u; } v; v.f = x;
  u32 r = v.u + 0x7FFFu + ((v.u >> 16) & 1u);  // round-to-nearest-even
  return (u16)(r >> 16);
}
#if __has_builtin(__builtin_amdgcn_cvt_pk_bf16_f32)
typedef __attribute__((ext_vector_type(2))) __bf16 bf162_t;
__device__ inline u32 pk2(float a, float b) {   // v_cvt_pk_bf16_f32: low=a, high=b, RNE
  union { bf162_t v; u32 u; } cv;
  cv.v = __builtin_amdgcn_cvt_pk_bf16_f32(a, b);
  return cv.u;
}
#else
__device__ inline u32 pk2(float a, float b) {
  return (u32)f2bf(a) | ((u32)f2bf(b) << 16);
}
#endif

// ---------- fused prologue: X fp32->bf16 (blocks 0..4095), W transposes (4096..8191) ----------
__global__ __launch_bounds__(256) void prologue(const float* __restrict__ X,
                                                const float* __restrict__ Wq, const float* __restrict__ Wk,
                                                const float* __restrict__ Wv, const float* __restrict__ Wo,
                                                u16* __restrict__ Xb, u16* __restrict__ WqkvT,
                                                u16* __restrict__ WoT) {
  __shared__ float tls[32][33];
  int bid = blockIdx.x;
  if (bid < 4096) {
    int i = bid * 256 + threadIdx.x;  // one float4 per thread
    float4_t x = ((const float4_t*)X)[i];
    union { u32 u[2]; u64 ll; } o;
    o.u[0] = pk2(x[0], x[1]);
    o.u[1] = pk2(x[2], x[3]);
    ((u64*)Xb)[i] = o.ll;
  } else {
    int t = bid - 4096;
    int mat = t >> 10, tile = t & 1023;
    const float* W = (mat == 0) ? Wq : (mat == 1) ? Wk : (mat == 2) ? Wv : Wo;
    u16* WT = (mat < 3) ? WqkvT + ((size_t)mat << 20) : WoT;
    int tx = threadIdx.x & 31, ty = threadIdx.x >> 5;  // 32 x 8
    int c0 = (tile & 31) * 32, r0 = (tile >> 5) * 32;  // r0: k, c0: n
    #pragma unroll
    for (int i = 0; i < 4; ++i)
      tls[ty + i * 8][tx] = W[(r0 + ty + i * 8) * 1024 + c0 + tx];
    __syncthreads();
    #pragma unroll
    for (int i = 0; i < 4; ++i)
      WT[(size_t)(c0 + ty + i * 8) * 1024 + r0 + tx] = f2bf(tls[tx][ty + i * 8]);
  }
}

// ---------- GEMM: 128x128 C-tile, 4 waves each 64x64, BK=64, VGPR-pipelined staging ----------
// r10 change: staging goes global->VGPR->ds_write (r9-proven idiom) instead of
// global_load_lds, so barriers no longer drain vmcnt(0) on in-flight staging loads;
// the next k-slab's loads issue right after barrier 1 and land during 32 MFMAs.
// Global sources are LINEAR (coalesced); the XOR chunk swizzle is applied at the LDS
// DEST, so fragment ds_read_b128 stays 2-way (free) and ds_write is 2-way (free).
// mode 4 (fused QKV, 768 blocks): col block 0->Q(x0.125) o0 [B,H,S,64], 1->K o1,
//   2->V o2 [B,H,64,S] (transposed). mode 3 (O-proj, 256 blocks): fp32 out o0.
__global__ __launch_bounds__(256) void gemm128(const u16* __restrict__ A, const u16* __restrict__ BT,
                                               const float* __restrict__ bias0, const float* __restrict__ bias1,
                                               const float* __restrict__ bias2,
                                               void* __restrict__ o0, void* __restrict__ o1, void* __restrict__ o2,
                                               int mode) {
  __shared__ __align__(16) u16 Als[128 * 64];  // 16 KB
  __shared__ __align__(16) u16 Bls[128 * 64];  // 16 KB
  int g = blockIdx.x, m0t, n0t;
  if (mode == 4) {  // 768 blocks: panels of 16 m-tiles x 24 n-tiles
    int mh = g / 384, r = g - mh * 384;
    n0t = r >> 4;
    m0t = mh * 16 + (r & 15);
  } else {          // 256 blocks
    m0t = g & 31;
    n0t = g >> 5;
  }
  const int m0 = m0t * 128, n0 = n0t * 128;
  const int lane = threadIdx.x & 63, wave = threadIdx.x >> 6;
  const int quad = lane >> 4, c = lane & 15;
  const int wm = wave >> 1, wn = wave & 1;

  // staging lanes: 8 rows x 8 chunks(16B) per call; wave covers 32 rows via 4 calls
  const int srow = lane >> 3, schunk = lane & 7;
  int soff[4], dst[4];
  #pragma unroll
  for (int q = 0; q < 4; ++q) {
    int r = wave * 32 + q * 8 + srow;
    soff[q] = r * 1024 + (schunk << 3);                 // linear global
    dst[q]  = r * 64 + ((schunk ^ (r & 7)) << 3);       // XOR-swizzled LDS dest
  }
  const u16* gA = A + (size_t)m0 * 1024;
  const u16* gB = BT + (size_t)n0 * 1024;

  int ar[2][4], br[2][4];
  #pragma unroll
  for (int ko = 0; ko < 2; ++ko) {
    #pragma unroll
    for (int i = 0; i < 4; ++i) {
      int rowa = wm * 64 + i * 16 + c;
      ar[ko][i] = rowa * 64 + (((ko * 4 + quad) ^ (rowa & 7)) << 3);
      int rowb = wn * 64 + i * 16 + c;
      br[ko][i] = rowb * 64 + (((ko * 4 + quad) ^ (rowb & 7)) << 3);
    }
  }

  // prefetch slab 0 into VGPRs
  short8_t ra[4], rb[4];
  #pragma unroll
  for (int q = 0; q < 4; ++q) ra[q] = *(const short8_t*)(gA + soff[q]);
  #pragma unroll
  for (int q = 0; q < 4; ++q) rb[q] = *(const short8_t*)(gB + soff[q]);

  float4_t acc[4][4] = {};
  for (int k0 = 0; k0 < 1024; k0 += 64) {
    // commit prefetched slab to LDS
    #pragma unroll
    for (int q = 0; q < 4; ++q) *(short8_t*)&Als[dst[q]] = ra[q];
    #pragma unroll
    for (int q = 0; q < 4; ++q) *(short8_t*)&Bls[dst[q]] = rb[q];
    __syncthreads();
    // issue next slab's loads now; latency hides under the 32 MFMAs below
    if (k0 < 960) {
      #pragma unroll
      for (int q = 0; q < 4; ++q) ra[q] = *(const short8_t*)(gA + soff[q] + k0 + 64);
      #pragma unroll
      for (int q = 0; q < 4; ++q) rb[q] = *(const short8_t*)(gB + soff[q] + k0 + 64);
    }
    #pragma unroll
    for (int ko = 0; ko < 2; ++ko) {
      short8_t af[4], bfr[4];
      #pragma unroll
      for (int i = 0; i < 4; ++i) af[i] = *(const short8_t*)&Als[ar[ko][i]];
      #pragma unroll
      for (int j = 0; j < 4; ++j) bfr[j] = *(const short8_t*)&Bls[br[ko][j]];
      #pragma unroll
      for (int i = 0; i < 4; ++i)
        #pragma unroll
        for (int j = 0; j < 4; ++j)
          acc[i][j] = __builtin_amdgcn_mfma_f32_16x16x32_bf16(af[i], bfr[j], acc[i][j], 0, 0, 0);
    }
    __syncthreads();  // all reads done before next commit (single LDS buffer)
  }

  const int mrow = m0 + wm * 64, ncol = n0 + wn * 64;
  if (mode == 3) {
    float* o = (float*)o0;
    #pragma unroll
    for (int i = 0; i < 4; ++i) {
      #pragma unroll
      for (int j = 0; j < 4; ++j) {
        int colb = ncol + j * 16 + c;
        float bv = bias0[colb];
        int rowb = mrow + i * 16 + quad * 4;
        #pragma unroll
        for (int r = 0; r < 4; ++r)
          o[(size_t)(rowb + r) * 1024 + colb] = acc[i][j][r] + bv;
      }
    }
  } else {
    #pragma unroll
    for (int j = 0; j < 4; ++j) {
      int colb = ncol + j * 16 + c;     // 0..3071
      int which = colb >> 10;           // 0:Q 1:K 2:V (uniform per j)
      int n1 = colb & 1023, h = n1 >> 6, d = n1 & 63;
      const float* bp = (which == 0) ? bias0 : (which == 1 ? bias1 : bias2);
      float bv = bp[n1];
      #pragma unroll
      for (int i = 0; i < 4; ++i) {
        int rowb = mrow + i * 16 + quad * 4;
        int b = rowb >> 11, s = rowb & 2047;
        if (which == 2) {
          u16* o = (u16*)o2 + (((size_t)(b * 16 + h) * 64 + d) * 2048 + s);
          union { u32 u[2]; u64 ll; } ov;
          ov.u[0] = pk2(acc[i][j][0] + bv, acc[i][j][1] + bv);
          ov.u[1] = pk2(acc[i][j][2] + bv, acc[i][j][3] + bv);
          *(u64*)o = ov.ll;
        } else {
          float sc = (which == 0) ? 0.125f : 1.0f;
          u16* o = (u16*)((which == 0) ? o0 : o1);
          #pragma unroll
          for (int r = 0; r < 4; ++r)
            o[(((size_t)(b * 16 + h) * 2048 + (s + r)) << 6) + d] = f2bf((acc[i][j][r] + bv) * sc);
        }
      }
    }
  }
}

// P^T C-layout -> 16x16x32 B-operand layout via packed-bf16 shuffles (proven r2-r9)
__device__ inline short8_t p_to_b32(const float* p, int quad, int c) {
  u32 pk0[2] = {pk2(p[0], p[1]), pk2(p[2], p[3])};
  u32 pk1[2] = {pk2(p[4], p[5]), pk2(p[6], p[7])};
  int base = ((quad & 1) * 2) * 16 + c;
  union { u32 u[4]; short8_t v; } pf;
  #pragma unroll
  for (int x = 0; x < 4; ++x) {
    int src = base + ((x >> 1) << 4);
    int v0 = __shfl((int)pk0[x & 1], src);
    int v1 = __shfl((int)pk1[x & 1], src);
    pf.u[x] = (quad < 2) ? (u32)v0 : (u32)v1;
  }
  return pf.v;
}

// ---------- flash attention: 64-query tile per block, dbuf LDS, 1 barrier/tile ----------
// Q,K: [B,H,S,64] bf16 (Q pre-scaled 1/8); VT: [B,H,64,S]; ctx: [B,S,1024] bf16.
// Grid 1024 x 256 (4 blocks/CU vs r9's 2): block = (bh, 64-query tile qt).
// bh = (g&7)*4+((g>>3)&3) (XCD L2 affinity); qt = u<16 ? 31-u : u-16 -> heavy tiles
// dispatch first, pairs (g, g+512) sum to 31 tiles (uniform CU load).
// 4 waves each own 16 queries. Per 64-key tile: K (64x64) and V^T (64x64) staged
// into the PARITY LDS buffer via VGPR prefetch (loaded during previous tile's
// compute) -> exactly ONE barrier per tile, no staging drain on the critical path.
// Linear global sources; XOR swizzle at LDS dest (ds_write and ds_read both 2-way-free).
// Fixed-base softmax (no running max; masked -> exp2(-50)=0); causal select only on
// the diagonal tile; l reduced across quads at the end.
__global__ __launch_bounds__(256, 4) void attn_kernel(const u16* __restrict__ Q, const u16* __restrict__ K,
                                                      const u16* __restrict__ VT, const float* __restrict__ mask,
                                                      u16* __restrict__ ctx) {
  __shared__ __align__(16) u16 Kls[2 * 64 * 64];  // 2 x 8 KB, [key][d] swizzled
  __shared__ __align__(16) u16 Vls[2 * 64 * 64];  // 2 x 8 KB, [d][key] swizzled
  const float C1 = 10000.0f * 1.4426950408889634f;
  const float LOG2E = 1.4426950408889634f;
  int w = threadIdx.x >> 6, lane = threadIdx.x & 63;
  int quad = lane >> 4, c = lane & 15;
  int g = blockIdx.x;
  int bh = (g & 7) * 4 + ((g >> 3) & 3);
  int u = g >> 5;                            // 0..31
  int qt = (u < 16) ? (31 - u) : (u - 16);   // heavy first; pairs (g,g+512) sum to 31
  int b = bh >> 4, h = bh & 15;
  const u16* Kp = K + ((size_t)bh << 17);
  const u16* Vp = VT + ((size_t)bh << 17);
  const float* mp = mask + (b << 11);
  int q0 = qt * 64 + w * 16;

  // Q^T B-operand fragment (16 queries per wave)
  const u16* Qp = Q + (((size_t)bh * 2048 + q0 + c) << 6) + quad * 8;
  short8_t qf0 = *(const short8_t*)(Qp);
  short8_t qf1 = *(const short8_t*)(Qp + 32);

  // staging: 64 rows x 8 chunks(16B) per tile; wave w covers rows w*16..+15 (2 calls)
  const int srow = lane >> 3, schunk = lane & 7;
  const u16* gK[2]; const u16* gV[2]; int dK[2], dV[2];
  #pragma unroll
  for (int i = 0; i < 2; ++i) {
    int R = w * 16 + i * 8 + srow;           // key row (K) / d row (V)
    gK[i] = Kp + R * 64 + (schunk << 3);                 // linear source
    dK[i] = R * 64 + ((schunk ^ (R & 7)) << 3);          // swizzled dest
    gV[i] = Vp + (size_t)R * 2048 + (schunk << 3);
    dV[i] = R * 64 + ((schunk ^ (R & 7)) << 3);
  }

  // fragment read offsets with matching swizzle
  int koff[4][2];
  #pragma unroll
  for (int kg = 0; kg < 4; ++kg) {
    int r = kg * 16 + c;
    #pragma unroll
    for (int ko = 0; ko < 2; ++ko)
      koff[kg][ko] = r * 64 + (((ko * 4 + quad) ^ (r & 7)) << 3);
  }
  int voff[4][2];
  #pragma unroll
  for (int dblk = 0; dblk < 4; ++dblk) {
    int d = dblk * 16 + c;
    #pragma unroll
    for (int kc = 0; kc < 2; ++kc)
      voff[dblk][kc] = d * 64 + (((kc * 4 + quad) ^ (d & 7)) << 3);
  }

  int ke[8];
  #pragma unroll
  for (int e = 0; e < 8; ++e) ke[e] = ((e >> 2) << 4) + quad * 4 + (e & 3);
  int thr = w * 16 + c;  // causal threshold within the diagonal tile

  float4_t O[4] = {};
  float l = 0.0f;

  // prefetch tile 0 into VGPRs
  short8_t kreg[2], vreg[2];
  #pragma unroll
  for (int i = 0; i < 2; ++i) { kreg[i] = *(const short8_t*)(gK[i]); vreg[i] = *(const short8_t*)(gV[i]); }

  for (int t = 0; t <= qt; ++t) {
    int kb = t << 6;
    int bufo = (t & 1) << 12;  // 4096 u16 per buffer
    #pragma unroll
    for (int i = 0; i < 2; ++i) *(short8_t*)&Kls[bufo + dK[i]] = kreg[i];
    #pragma unroll
    for (int i = 0; i < 2; ++i) *(short8_t*)&Vls[bufo + dV[i]] = vreg[i];
    __syncthreads();
    if (t < qt) {  // issue tile t+1 loads; land during this tile's compute
      int kb2 = (t + 1) << 6;
      #pragma unroll
      for (int i = 0; i < 2; ++i) {
        kreg[i] = *(const short8_t*)(gK[i] + (size_t)kb2 * 64);
        vreg[i] = *(const short8_t*)(gV[i] + kb2);
      }
    }
    // ---- S^T = K_tile @ Q^T (8 MFMA) ----
    float4_t s[4];
    #pragma unroll
    for (int kg = 0; kg < 4; ++kg) {
      short8_t k0 = *(const short8_t*)&Kls[bufo + koff[kg][0]];
      short8_t k1 = *(const short8_t*)&Kls[bufo + koff[kg][1]];
      float4_t a = {};
      a = __builtin_amdgcn_mfma_f32_16x16x32_bf16(k0, qf0, a, 0, 0, 0);
      a = __builtin_amdgcn_mfma_f32_16x16x32_bf16(k1, qf1, a, 0, 0, 0);
      s[kg] = a;
    }
    // ---- masks + fixed-base softmax + C->B transform ----
    float4_t mpl[4];
    #pragma unroll
    for (int kg = 0; kg < 4; ++kg)
      mpl[kg] = (*(const float4_t*)(mp + kb + kg * 16 + quad * 4) - 1.0f) * C1;
    bool diag = (t == qt);
    short8_t pf[2];
    #pragma unroll
    for (int kc = 0; kc < 2; ++kc) {
      float p[8];
      #pragma unroll
      for (int e = 0; e < 8; ++e) {
        int kg = kc * 2 + (e >> 2);
        p[e] = __builtin_fmaf(s[kg][e & 3], LOG2E, mpl[kg][e & 3]);
      }
      if (diag) {
        #pragma unroll
        for (int e = 0; e < 8; ++e) {
          int ko2 = kc * 32 + ke[e];
          p[e] = (ko2 > thr) ? -50.0f : p[e];
        }
      }
      #pragma unroll
      for (int e = 0; e < 8; ++e) {
        float pe = exp2f(p[e]);
        p[e] = pe;
        l += pe;
      }
      pf[kc] = p_to_b32(p, quad, c);
    }
    // ---- ctx^T += V^T_tile @ P^T (8 MFMA) ----
    #pragma unroll
    for (int dblk = 0; dblk < 4; ++dblk) {
      #pragma unroll
      for (int kc = 0; kc < 2; ++kc) {
        short8_t vf = *(const short8_t*)&Vls[bufo + voff[dblk][kc]];
        O[dblk] = __builtin_amdgcn_mfma_f32_16x16x32_bf16(vf, pf[kc], O[dblk], 0, 0, 0);
      }
    }
    // no trailing barrier: next tile writes the OTHER buffer; its leading barrier
    // orders those writes after every wave's reads of this buffer.
  }
  // ---- epilogue: reduce l across quads, normalize, store ----
  l += __shfl_xor(l, 16);
  l += __shfl_xor(l, 32);
  float rl = 1.0f / l;
  u16* op = ctx + ((size_t)(b * 2048 + q0 + c) * 1024 + h * 64 + quad * 4);
  #pragma unroll
  for (int dblk = 0; dblk < 4; ++dblk) {
    union { u32 uu[2]; u64 ll; } ov;
    ov.uu[0] = pk2(O[dblk][0] * rl, O[dblk][1] * rl);
    ov.uu[1] = pk2(O[dblk][2] * rl, O[dblk][3] * rl);
    *(u64*)(op + dblk * 16) = ov.ll;
  }
}

// ---------- launch ----------
extern "C" void kernel_launch(void* const* d_in, const int* in_sizes, int n_in,
                              void* d_out, int out_size, void* d_ws, size_t ws_size,
                              hipStream_t stream) {
  const float* X    = (const float*)d_in[0];
  const float* mask = (const float*)d_in[1];
  const float* Wq   = (const float*)d_in[2];
  const float* bq   = (const float*)d_in[3];
  const float* Wk   = (const float*)d_in[4];
  const float* bk   = (const float*)d_in[5];
  const float* Wv   = (const float*)d_in[6];
  const float* bv   = (const float*)d_in[7];
  const float* Wo   = (const float*)d_in[8];
  const float* bo   = (const float*)d_in[9];

  char* w = (char*)d_ws;
  u16* Xb     = (u16*)(w);                 // 8 MB  [4096,1024] bf16
  u16* WqkvT  = (u16*)(w + (8ull  << 20)); // 6 MB  [3072,1024] bf16 (Q|K|V transposed)
  u16* WoT    = (u16*)(w + (14ull << 20)); // 2 MB  [1024,1024] bf16
  u16* Qb     = (u16*)(w + (16ull << 20)); // 8 MB [B,H,S,64]
  u16* Kb     = (u16*)(w + (24ull << 20)); // 8 MB [B,H,S,64]
  u16* VTb    = (u16*)(w + (32ull << 20)); // 8 MB [B,H,64,S]
  u16* Ctx    = (u16*)(w + (40ull << 20)); // 8 MB [4096,1024]

  prologue<<<8192, 256, 0, stream>>>(X, Wq, Wk, Wv, Wo, Xb, WqkvT, WoT);
  gemm128<<<768, 256, 0, stream>>>(Xb, WqkvT, bq, bk, bv, Qb, Kb, VTb, 4);
  attn_kernel<<<1024, 256, 0, stream>>>(Qb, Kb, VTb, mask, Ctx);
  gemm128<<<256, 256, 0, stream>>>(Ctx, WoT, bo, bo, bo, d_out, d_out, d_out, 3);
}